// Round 4
// baseline (179.740 us; speedup 1.0000x reference)
//
#include <hip/hip_runtime.h>

typedef __attribute__((ext_vector_type(8))) short short8;
typedef __attribute__((ext_vector_type(4))) float floatx4;

#define NTYPES 64
#define BPT 16   // blocks per type; grid = (BPT, NTYPES); 4 waves/block => 64 wave-slots/type
#define NB  64   // histogram blocks (segments)

// ws layout (ints):
#define WS_HIST   0
#define WS_SCAN   4096
#define WS_CNT    8192
#define WS_OFF    8256
#define WS_LIST   8320

// LDS (ushorts): weights bf16 transposed [o][k] with scale folded; then
// 4 per-wave scratch regions (16 rows x 248 ushorts, 496B row = 31x16B).
// The scratch is reused per-irrep as the fp32 output-staging buffer after
// the A-fragments have been read (DS ops from one wave are in-order).
#define WT0_OFF 0        // 64 rows x 72  (k<64)
#define WT1_OFF 4608     // 32 rows x 40  (k<32)
#define WT2_OFF 5888     // 16 rows x 40  (k<16 data, k16..31 zero)
#define WT_END  6528
#define XS_USH  3968     // 16 x 248
#define SMEM_USH (WT_END + 4 * XS_USH)   // 22400 ushorts = 44.8 KB

__device__ __forceinline__ unsigned short f2bf(float f) {
    union { float f; unsigned u; } v; v.f = f;
    unsigned u = v.u;
    u += 0x7FFFu + ((u >> 16) & 1u);   // round-to-nearest-even
    return (unsigned short)(u >> 16);
}

// ---- pass 1: per-segment LDS histogram -> hist[type][block] ----
__global__ __launch_bounds__(256) void hist_kernel(const int* __restrict__ idx,
                                                   int* __restrict__ ws, int n) {
    __shared__ int h[NTYPES];
    const int b = blockIdx.x, tid = threadIdx.x;
    if (tid < NTYPES) h[tid] = 0;
    __syncthreads();
    const int seg = (n + NB - 1) / NB;
    const int lo = b * seg, hi = min(lo + seg, n);
    for (int e = lo + tid; e < hi; e += 256) atomicAdd(&h[idx[e]], 1);
    __syncthreads();
    if (tid < NTYPES) ws[WS_HIST + tid * NB + b] = h[tid];
}

// ---- pass 2: exclusive scan of 4096-entry histogram (one block) ----
__global__ __launch_bounds__(256) void scan_kernel(int* __restrict__ ws, int n) {
    __shared__ int partial[256];
    const int tid = threadIdx.x;
    int v[16];
    int s = 0;
    const int base = tid * 16;
#pragma unroll
    for (int k = 0; k < 16; ++k) { v[k] = ws[WS_HIST + base + k]; s += v[k]; }
    partial[tid] = s;
    __syncthreads();
    for (int d = 1; d < 256; d <<= 1) {
        int t = (tid >= d) ? partial[tid - d] : 0;
        __syncthreads();
        partial[tid] += t;
        __syncthreads();
    }
    int excl = (tid == 0) ? 0 : partial[tid - 1];
#pragma unroll
    for (int k = 0; k < 16; ++k) { ws[WS_SCAN + base + k] = excl; excl += v[k]; }
    __syncthreads();
    if (tid < NTYPES) {
        int start = ws[WS_SCAN + tid * NB];
        int end   = (tid == NTYPES - 1) ? partial[255] : ws[WS_SCAN + (tid + 1) * NB];
        ws[WS_OFF + tid] = start;
        ws[WS_CNT + tid] = end - start;
    }
}

// ---- pass 3: scatter via LDS cursors (no global atomics) ----
__global__ __launch_bounds__(256) void scatter_kernel(const int* __restrict__ idx,
                                                      int* __restrict__ ws, int n) {
    __shared__ int cur[NTYPES];
    const int b = blockIdx.x, tid = threadIdx.x;
    if (tid < NTYPES) cur[tid] = ws[WS_SCAN + tid * NB + b];
    __syncthreads();
    const int seg = (n + NB - 1) / NB;
    const int lo = b * seg, hi = min(lo + seg, n);
    for (int e = lo + tid; e < hi; e += 256) {
        int pos = atomicAdd(&cur[idx[e]], 1);
        ws[WS_LIST + pos] = e;
    }
}

// ---- main: one wave = 16 nodes; all global I/O coalesced float4; all
// ---- layout transforms via per-wave LDS; no barriers in the node loop.
__global__ __launch_bounds__(256, 3) void main_kernel(
    const float* __restrict__ x,
    const float* __restrict__ W0,
    const float* __restrict__ W1,
    const float* __restrict__ W2,
    const int* __restrict__ ws,
    float* __restrict__ out)
{
    __shared__ __align__(16) unsigned short sm[SMEM_USH];
    float* smf = (float*)sm;

    const int ty  = blockIdx.y;
    const int tid = threadIdx.x;

    // ---- stage weights once: bf16, transposed [o][k], scale folded ----
    {
        const float* w = W0 + (size_t)ty * 64 * 64;       // [i][o]
        for (int e = tid; e < 4096; e += 256) {
            int i = e >> 6, o = e & 63;
            sm[WT0_OFF + o * 72 + i] = f2bf(w[e] * 0.125f);
        }
        const float* w1 = W1 + (size_t)ty * 32 * 32;
        for (int e = tid; e < 1024; e += 256) {
            int i = e >> 5, o = e & 31;
            sm[WT1_OFF + o * 40 + i] = f2bf(w1[e] * 0.17677669529663687f);
        }
        const float* w2 = W2 + (size_t)ty * 16 * 16;
        {
            int e = tid & 255;
            int i = e >> 4, o = e & 15;
            sm[WT2_OFF + o * 40 + i]      = f2bf(w2[e] * 0.25f);
            sm[WT2_OFF + o * 40 + 16 + i] = 0;            // K-pad 16..31
        }
    }
    __syncthreads();

    const int cnt = ws[WS_CNT + ty];
    const int off = ws[WS_OFF + ty];
    const int* list = ws + WS_LIST;

    const int wv = tid >> 6, ln = tid & 63;
    const int r = ln & 15, q4 = ln >> 4;     // frag row / k-quad
    const int XS = WT_END + wv * XS_USH;     // per-wave scratch (ushort idx)
    const int FB = XS >> 1;                  // same region as float idx
    const int slot = blockIdx.x * 4 + wv;

    for (int base = slot * 16; base < cnt; base += BPT * 4 * 16) {
        int gi = min(base + r, cnt - 1);
        int nd = list[off + gi];             // lane l<16 holds node of row l

        // ---- stage 16 rows x 240 floats -> bf16 LDS (coalesced f4 loads)
#pragma unroll
        for (int t = 0; t < 15; ++t) {
            int idx = t * 64 + ln;
            int row = idx / 60, c4 = idx - row * 60;
            int nod = __shfl(nd, row);
            float4 f = *(const float4*)(x + (size_t)nod * 240 + c4 * 4);
            ushort4 u;
            u.x = f2bf(f.x); u.y = f2bf(f.y); u.z = f2bf(f.z); u.w = f2bf(f.w);
            *(ushort4*)(sm + XS + row * 248 + c4 * 4) = u;
        }

        // ---- read ALL A-fragments (x-stage is dead afterwards)
        short8 a00 = *(const short8*)(sm + XS + r * 248 + q4 * 8);
        short8 a01 = *(const short8*)(sm + XS + r * 248 + 32 + q4 * 8);
        short8 a1[3];
#pragma unroll
        for (int d = 0; d < 3; ++d)
#pragma unroll
            for (int j = 0; j < 8; ++j)
                ((unsigned short*)&a1[d])[j] = sm[XS + r * 248 + 64 + (q4 * 8 + j) * 3 + d];
        short8 a2[5];
#pragma unroll
        for (int d = 0; d < 5; ++d) {
            a2[d] = short8{0, 0, 0, 0, 0, 0, 0, 0};
            if (q4 < 2)
#pragma unroll
                for (int j = 0; j < 8; ++j)
                    ((unsigned short*)&a2[d])[j] = sm[XS + r * 248 + 160 + (q4 * 8 + j) * 5 + d];
        }

        // ================= irrep0: M=16 N=64 K=64, out-stride 68 =================
        {
            floatx4 acc[4];
#pragma unroll
            for (int nt = 0; nt < 4; ++nt) {
                short8 b0 = *(const short8*)(sm + WT0_OFF + (nt * 16 + r) * 72 + q4 * 8);
                short8 b1 = *(const short8*)(sm + WT0_OFF + (nt * 16 + r) * 72 + 32 + q4 * 8);
                acc[nt] = floatx4{0.f, 0.f, 0.f, 0.f};
                acc[nt] = __builtin_amdgcn_mfma_f32_16x16x32_bf16(a00, b0, acc[nt], 0, 0, 0);
                acc[nt] = __builtin_amdgcn_mfma_f32_16x16x32_bf16(a01, b1, acc[nt], 0, 0, 0);
            }
#pragma unroll
            for (int nt = 0; nt < 4; ++nt)
#pragma unroll
                for (int rr = 0; rr < 4; ++rr)
                    smf[FB + (q4 * 4 + rr) * 68 + nt * 16 + r] = acc[nt][rr];
#pragma unroll
            for (int t = 0; t < 4; ++t) {
                int idx = t * 64 + ln;
                int row = idx >> 4, c4 = idx & 15;
                float4 v = *(const float4*)(smf + FB + row * 68 + c4 * 4);
                int nod = __shfl(nd, row);
                if (base + row < cnt) *(float4*)(out + (size_t)nod * 240 + c4 * 4) = v;
            }
        }

        // ================= irrep1: per d: M=16 N=32 K=32, out-stride 100 =================
        {
            short8 b0 = *(const short8*)(sm + WT1_OFF + r * 40 + q4 * 8);
            short8 b1 = *(const short8*)(sm + WT1_OFF + (16 + r) * 40 + q4 * 8);
            floatx4 acc[6];
#pragma unroll
            for (int d = 0; d < 3; ++d) {
                acc[d * 2]     = floatx4{0.f, 0.f, 0.f, 0.f};
                acc[d * 2]     = __builtin_amdgcn_mfma_f32_16x16x32_bf16(a1[d], b0, acc[d * 2], 0, 0, 0);
                acc[d * 2 + 1] = floatx4{0.f, 0.f, 0.f, 0.f};
                acc[d * 2 + 1] = __builtin_amdgcn_mfma_f32_16x16x32_bf16(a1[d], b1, acc[d * 2 + 1], 0, 0, 0);
            }
#pragma unroll
            for (int d = 0; d < 3; ++d)
#pragma unroll
                for (int h = 0; h < 2; ++h)
#pragma unroll
                    for (int rr = 0; rr < 4; ++rr)
                        smf[FB + (q4 * 4 + rr) * 100 + (h * 16 + r) * 3 + d] = acc[d * 2 + h][rr];
#pragma unroll
            for (int t = 0; t < 6; ++t) {
                int idx = t * 64 + ln;
                int row = idx / 24, c4 = idx - row * 24;
                float4 v = *(const float4*)(smf + FB + row * 100 + c4 * 4);
                int nod = __shfl(nd, row);
                if (base + row < cnt) *(float4*)(out + (size_t)nod * 240 + 64 + c4 * 4) = v;
            }
        }

        // ================= irrep2: per d: M=16 N=16 K=16(pad32), out-stride 84 =================
        {
            short8 b = *(const short8*)(sm + WT2_OFF + r * 40 + q4 * 8);
            floatx4 acc[5];
#pragma unroll
            for (int d = 0; d < 5; ++d) {
                acc[d] = floatx4{0.f, 0.f, 0.f, 0.f};
                acc[d] = __builtin_amdgcn_mfma_f32_16x16x32_bf16(a2[d], b, acc[d], 0, 0, 0);
            }
#pragma unroll
            for (int d = 0; d < 5; ++d)
#pragma unroll
                for (int rr = 0; rr < 4; ++rr)
                    smf[FB + (q4 * 4 + rr) * 84 + r * 5 + d] = acc[d][rr];
#pragma unroll
            for (int t = 0; t < 5; ++t) {
                int idx = t * 64 + ln;
                int row = idx / 20, c4 = idx - row * 20;
                float4 v = *(const float4*)(smf + FB + row * 84 + c4 * 4);
                int nod = __shfl(nd, row);
                if (base + row < cnt) *(float4*)(out + (size_t)nod * 240 + 160 + c4 * 4) = v;
            }
        }
    }
}

extern "C" void kernel_launch(void* const* d_in, const int* in_sizes, int n_in,
                              void* d_out, int out_size, void* d_ws, size_t ws_size,
                              hipStream_t stream) {
    const float* x  = (const float*)d_in[0];
    const float* W0 = (const float*)d_in[1];
    const float* W1 = (const float*)d_in[2];
    const float* W2 = (const float*)d_in[3];
    const int*   idx = (const int*)d_in[4];
    float* out = (float*)d_out;
    const int n = in_sizes[4];          // 65536 nodes
    int* ws = (int*)d_ws;

    hist_kernel   <<<NB, 256, 0, stream>>>(idx, ws, n);
    scan_kernel   <<<1, 256, 0, stream>>>(ws, n);
    scatter_kernel<<<NB, 256, 0, stream>>>(idx, ws, n);
    main_kernel   <<<dim3(BPT, NTYPES), 256, 0, stream>>>(x, W0, W1, W2, ws, out);
}

// Round 5
// 160.895 us; speedup vs baseline: 1.1171x; 1.1171x over previous
//
#include <hip/hip_runtime.h>

typedef __attribute__((ext_vector_type(8))) short short8;
typedef __attribute__((ext_vector_type(4))) float floatx4;

#define NTYPES   64
#define ROWS_PB  256     // nodes per block (contiguous span -> streaming HBM)
#define THREADS  512     // 8 waves
#define NW       8
#define MAXTILES 80      // sum ceil(c_t/16) <= 64 + 256/16 - ... <= 76
#define WT_STRIDE 5632   // ushorts per type in transposed weight array

__device__ __forceinline__ unsigned short f2bf(float f) {
    union { float f; unsigned u; } v; v.f = f;
    unsigned u = v.u;
    u += 0x7FFFu + ((u >> 16) & 1u);   // round-to-nearest-even
    return (unsigned short)(u >> 16);
}

// ---- pre-pass: transpose weights to bf16, MFMA-frag-major, scale folded ----
// Layout per type (ushorts, base ty*5632):
//   irrep0: f in [0,8) = (nt*2+h):  [f*512 + r*32 + k2]  = W0[i=h*32+k2][o=nt*16+r]*s0
//   irrep1: h in [0,2):  [4096 + h*512 + r*32 + k]       = W1[i=k][o=h*16+r]*s1
//   irrep2:              [5120 + r*32 + k] (k<16 data)   = W2[i=k][o=r]*s2, k>=16 -> 0
__global__ __launch_bounds__(256) void wt_kernel(const float* __restrict__ W0,
                                                 const float* __restrict__ W1,
                                                 const float* __restrict__ W2,
                                                 unsigned short* __restrict__ wt) {
    const int t = blockIdx.x, tid = threadIdx.x;
    unsigned short* dst = wt + (size_t)t * WT_STRIDE;
    const float* w0 = W0 + (size_t)t * 4096;
    for (int e = tid; e < 4096; e += 256) {
        int f = e >> 9, rem = e & 511, rr = rem >> 5, k2 = rem & 31;
        int i = (f & 1) * 32 + k2, o = (f >> 1) * 16 + rr;
        dst[e] = f2bf(w0[i * 64 + o] * 0.125f);
    }
    const float* w1 = W1 + (size_t)t * 1024;
    for (int e = tid; e < 1024; e += 256) {
        int h = e >> 9, rem = e & 511, rr = rem >> 5, k = rem & 31;
        dst[4096 + e] = f2bf(w1[k * 32 + h * 16 + rr] * 0.17677669529663687f);
    }
    const float* w2 = W2 + (size_t)t * 256;
    for (int e = tid; e < 512; e += 256) {
        int rr = e >> 5, k = e & 31;
        dst[5120 + e] = (k < 16) ? f2bf(w2[k * 16 + rr] * 0.25f) : (unsigned short)0;
    }
}

// ---- main: one block = 256 consecutive nodes; local LDS counting sort by
// ---- type; padded 16-row MFMA tiles; B-frags coalesced from L2-resident wt.
__global__ __launch_bounds__(THREADS, 1) void main_kernel(
    const float* __restrict__ x,
    const int* __restrict__ gidx,
    const unsigned short* __restrict__ wt,
    float* __restrict__ out, int n)
{
    __shared__ __align__(16) unsigned short xrow[ROWS_PB * 240];  // 122.9 KB
    __shared__ int cnts[NTYPES], cur[NTYPES];
    __shared__ unsigned short tlist[ROWS_PB];
    __shared__ unsigned short ttype[MAXTILES], tstt[MAXTILES], trws[MAXTILES];
    __shared__ int ntiles;

    const int b = blockIdx.x, tid = threadIdx.x;
    const int nbase = b * ROWS_PB;
    const int nvalid = min(ROWS_PB, n - nbase);

    // ---- stage x span -> bf16 LDS (perfectly coalesced streaming reads) ----
#pragma unroll
    for (int t = 0; t < 30; ++t) {
        int e = t * THREADS + tid;
        int row = e / 60, c4 = e - row * 60;
        if (row < nvalid) {
            float4 f = *(const float4*)(x + (size_t)(nbase + row) * 240 + c4 * 4);
            ushort4 u;
            u.x = f2bf(f.x); u.y = f2bf(f.y); u.z = f2bf(f.z); u.w = f2bf(f.w);
            *(ushort4*)(xrow + row * 240 + c4 * 4) = u;
        }
    }

    // ---- local counting sort by type + tile build ----
    if (tid < NTYPES) cnts[tid] = 0;
    __syncthreads();
    int myty = -1;
    if (tid < nvalid) { myty = gidx[nbase + tid]; atomicAdd(&cnts[myty], 1); }
    __syncthreads();
    if (tid == 0) {
        int acc = 0, ntl = 0;
        for (int t = 0; t < NTYPES; ++t) {
            int c = cnts[t];
            cur[t] = acc;
            for (int s = 0; s < c; s += 16) {
                ttype[ntl] = (unsigned short)t;
                tstt[ntl]  = (unsigned short)(acc + s);
                trws[ntl]  = (unsigned short)min(16, c - s);
                ++ntl;
            }
            acc += c;
        }
        ntiles = ntl;
    }
    __syncthreads();
    if (tid < nvalid) { int p = atomicAdd(&cur[myty], 1); tlist[p] = (unsigned short)tid; }
    __syncthreads();

    const int wv = tid >> 6, ln = tid & 63;
    const int r = ln & 15, q4 = ln >> 4;
    const int NT = ntiles;

    for (int ti = wv; ti < NT; ti += NW) {
        const int ty = ttype[ti], st = tstt[ti], rows = trws[ti];
        const int lr = tlist[st + min(r, rows - 1)];        // local row for A-row r
        const unsigned short* xr = xrow + lr * 240;

        // A-fragments from LDS
        short8 a00 = *(const short8*)(xr + q4 * 8);
        short8 a01 = *(const short8*)(xr + 32 + q4 * 8);
        short8 a1[3];
#pragma unroll
        for (int d = 0; d < 3; ++d)
#pragma unroll
            for (int j = 0; j < 8; ++j)
                ((unsigned short*)&a1[d])[j] = xr[64 + (q4 * 8 + j) * 3 + d];
        short8 a2[5];
#pragma unroll
        for (int d = 0; d < 5; ++d) {
            a2[d] = short8{0, 0, 0, 0, 0, 0, 0, 0};
            if (q4 < 2)
#pragma unroll
                for (int j = 0; j < 8; ++j)
                    ((unsigned short*)&a2[d])[j] = xr[160 + (q4 * 8 + j) * 5 + d];
        }

        // output row bases (C row = q4*4+rr; its local row sits in lane rowi)
        size_t ob[4]; bool vr[4];
#pragma unroll
        for (int rr = 0; rr < 4; ++rr) {
            int rowi = q4 * 4 + rr;
            vr[rr] = rowi < rows;
            int lrr = __shfl(lr, rowi);
            ob[rr] = (size_t)(nbase + lrr) * 240;
        }

        const unsigned short* wb = wt + (size_t)ty * WT_STRIDE;

        // ---- irrep0: M=16 N=64 K=64 ----
#pragma unroll
        for (int nt = 0; nt < 4; ++nt) {
            short8 b0 = *(const short8*)(wb + (nt * 2) * 512 + r * 32 + q4 * 8);
            short8 b1 = *(const short8*)(wb + (nt * 2 + 1) * 512 + r * 32 + q4 * 8);
            floatx4 ac = {0.f, 0.f, 0.f, 0.f};
            ac = __builtin_amdgcn_mfma_f32_16x16x32_bf16(a00, b0, ac, 0, 0, 0);
            ac = __builtin_amdgcn_mfma_f32_16x16x32_bf16(a01, b1, ac, 0, 0, 0);
#pragma unroll
            for (int rr = 0; rr < 4; ++rr)
                if (vr[rr]) out[ob[rr] + nt * 16 + r] = ac[rr];
        }

        // ---- irrep1: per d: M=16 N=32 K=32 ----
        {
            short8 c0 = *(const short8*)(wb + 4096 + r * 32 + q4 * 8);
            short8 c1 = *(const short8*)(wb + 4096 + 512 + r * 32 + q4 * 8);
#pragma unroll
            for (int d = 0; d < 3; ++d) {
                floatx4 ac = {0.f, 0.f, 0.f, 0.f};
                ac = __builtin_amdgcn_mfma_f32_16x16x32_bf16(a1[d], c0, ac, 0, 0, 0);
#pragma unroll
                for (int rr = 0; rr < 4; ++rr)
                    if (vr[rr]) out[ob[rr] + 64 + r * 3 + d] = ac[rr];
                floatx4 ac2 = {0.f, 0.f, 0.f, 0.f};
                ac2 = __builtin_amdgcn_mfma_f32_16x16x32_bf16(a1[d], c1, ac2, 0, 0, 0);
#pragma unroll
                for (int rr = 0; rr < 4; ++rr)
                    if (vr[rr]) out[ob[rr] + 64 + (16 + r) * 3 + d] = ac2[rr];
            }
        }

        // ---- irrep2: per d: M=16 N=16 K=16 (K-padded to 32) ----
        {
            short8 c2 = *(const short8*)(wb + 5120 + r * 32 + q4 * 8);
#pragma unroll
            for (int d = 0; d < 5; ++d) {
                floatx4 ac = {0.f, 0.f, 0.f, 0.f};
                ac = __builtin_amdgcn_mfma_f32_16x16x32_bf16(a2[d], c2, ac, 0, 0, 0);
#pragma unroll
                for (int rr = 0; rr < 4; ++rr)
                    if (vr[rr]) out[ob[rr] + 160 + r * 5 + d] = ac[rr];
            }
        }
    }
}

extern "C" void kernel_launch(void* const* d_in, const int* in_sizes, int n_in,
                              void* d_out, int out_size, void* d_ws, size_t ws_size,
                              hipStream_t stream) {
    const float* x  = (const float*)d_in[0];
    const float* W0 = (const float*)d_in[1];
    const float* W1 = (const float*)d_in[2];
    const float* W2 = (const float*)d_in[3];
    const int*   idx = (const int*)d_in[4];
    float* out = (float*)d_out;
    const int n = in_sizes[4];                 // 65536 nodes
    unsigned short* wt = (unsigned short*)d_ws; // 64*5632 ushorts = 720 KB

    wt_kernel  <<<NTYPES, 256, 0, stream>>>(W0, W1, W2, wt);
    main_kernel<<<(n + ROWS_PB - 1) / ROWS_PB, THREADS, 0, stream>>>(x, idx, wt, out, n);
}